// Round 16
// baseline (102.527 us; speedup 1.0000x reference)
//
#include <hip/hip_runtime.h>

// B=2, D=64, N=512, H=256, OUT=64
// mid[b] = sum_{c,i} relu( relu(hi[b,i,:]+hcb[b,c,:]) @ w2 + b2 ) @ w3 + N^2*b3
// out = relu(mid @ w4 + b4) @ w5 + b5
//
// big v16 = v15 producer/consumer skeleton, consumers switched to
// mfma_f32_16x16x32_bf16: 8 independent accumulator chains (2 row-blocks x
// 4 col-tiles, f32x4 accs = 32 regs) to cover MFMA dependent-issue latency.
// Producers write 16x16 fragment layout; prep emits 16x16-ordered B.

using f32x4   = __attribute__((ext_vector_type(4))) float;
using short8  = __attribute__((ext_vector_type(8))) short;
using float4v = __attribute__((ext_vector_type(4))) float;

__device__ __forceinline__ short f2bf(float f) {
    unsigned u = __float_as_uint(f);
    unsigned r = u + 0x7FFFu + ((u >> 16) & 1u);   // RNE
    return (short)(r >> 16);
}

__device__ __forceinline__ short8 relu_pack8(float4v lo, float4v hi4) {
#pragma unroll
    for (int e = 0; e < 4; ++e) {
        lo[e]  = fmaxf(lo[e], 0.f);
        hi4[e] = fmaxf(hi4[e], 0.f);
    }
    union { short8 s; unsigned u[4]; } r;
    asm("v_cvt_pk_bf16_f32 %0, %1, %2" : "=v"(r.u[0]) : "v"(lo[0]),  "v"(lo[1]));
    asm("v_cvt_pk_bf16_f32 %0, %1, %2" : "=v"(r.u[1]) : "v"(lo[2]),  "v"(lo[3]));
    asm("v_cvt_pk_bf16_f32 %0, %1, %2" : "=v"(r.u[2]) : "v"(hi4[0]), "v"(hi4[1]));
    asm("v_cvt_pk_bf16_f32 %0, %1, %2" : "=v"(r.u[3]) : "v"(hi4[2]), "v"(hi4[3]));
    return r.s;
}

// ---- prep: blocks [0,256): hi/hcb; [256,512): 16x16-fragment-ordered w2
__global__ __launch_bounds__(256) void prep(const float* __restrict__ in,
                                            const float* __restrict__ w1,
                                            const float* __restrict__ b1,
                                            const float* __restrict__ w2,
                                            float* __restrict__ hi,
                                            float* __restrict__ hcb,
                                            short* __restrict__ bfrag) {
    int tid = threadIdx.x;
    int bidx = blockIdx.x;
    if (bidx < 256) {
        int b = bidx >> 7, n0 = (bidx & 127) * 4;
        __shared__ float xs[4][64];
        {
            int nn = tid >> 6, d = tid & 63;
            xs[nn][d] = in[(size_t)(b * 64 + d) * 512 + n0 + nn];
        }
        __syncthreads();
        float a0[4] = {0.f, 0.f, 0.f, 0.f}, a1[4] = {0.f, 0.f, 0.f, 0.f};
#pragma unroll 8
        for (int d = 0; d < 64; ++d) {
            float wA = w1[d * 256 + tid];
            float wB = w1[(64 + d) * 256 + tid];
#pragma unroll
            for (int nn = 0; nn < 4; ++nn) {
                a0[nn] += xs[nn][d] * wA;
                a1[nn] += xs[nn][d] * wB;
            }
        }
        float bb = b1[tid];
#pragma unroll
        for (int nn = 0; nn < 4; ++nn) {
            size_t o = (size_t)(b * 512 + n0 + nn) * 256 + tid;
            hi[o]  = a0[nn];
            hcb[o] = a1[nn] + bb;
        }
    } else {
        // 16x16 B-frag: lane = lcol + 16*kg;  off = ((ct*8+q)*64 + lane)*8 + j
        // where k = q*32 + kg*8 + j, ncol = ct*16 + lcol
        int idx = (bidx - 256) * 256 + tid;        // [0, 65536)
        int k = idx >> 8, ncol = idx & 255;
        int ct = ncol >> 4, lcol = ncol & 15;
        int q = k >> 5, kg = (k >> 3) & 3, j = k & 7;
        int lane = lcol + 16 * kg;
        int off = ((ct * 8 + q) * 64 + lane) * 8 + j;
        bfrag[off] = f2bf(w2[k * 256 + ncol]);
    }
}

// ---- big v16: 256 blocks x 512 threads; ring 96 KB + flags
__global__ __launch_bounds__(512, 1) void big(const float* __restrict__ hi_,
                                              const float* __restrict__ hcb_,
                                              const short8* __restrict__ bfrag,
                                              const float* __restrict__ b2,
                                              float* __restrict__ partials) {
    __shared__ __align__(16) short8 ring[6][1024];   // slot: [Rb 2][q 8][lane 64]
    __shared__ unsigned ready_f[6];
    __shared__ unsigned done_f[6];

    const int tid = threadIdx.x;                  // 0..511
    const int bid = blockIdx.x;                   // [0,256)
    const int b = bid >> 7, cq = bid & 127;

    if (tid < 6) { ready_f[tid] = 0u; done_f[tid] = 4u; }
    __syncthreads();

    volatile unsigned* vready = ready_f;
    volatile unsigned* vdone  = done_f;

    const int w = tid >> 6, lane = tid & 63;
    const int l31 = lane & 31, h = lane >> 5;

    if (w < 4) {
        // ========== CONSUMER (one per SIMD): col-tiles 2w,2w+1,2w+8,2w+9 ==========
        const int cts[4] = {2 * w, 2 * w + 1, 2 * w + 8, 2 * w + 9};
        short8 bfr[4][8];
#pragma unroll
        for (int c = 0; c < 4; ++c)
#pragma unroll
            for (int q = 0; q < 8; ++q)
                bfr[c][q] = bfrag[(size_t)((cts[c] * 8 + q) * 64 + lane)];
        float b2v[4];
#pragma unroll
        for (int c = 0; c < 4; ++c) b2v[c] = b2[cts[c] * 16 + (lane & 15)];
        float js[4] = {0.f, 0.f, 0.f, 0.f};

#pragma unroll 1
        for (int t = 0; t < 64; ++t) {
            const int s = t % 6;
            while (vready[s] != (unsigned)(t + 1)) __builtin_amdgcn_s_sleep(1);
            const short8* __restrict__ slot = &ring[s][lane];

            f32x4 acc[2][4];   // [Rb][c] — 8 independent chains, 32 regs
#pragma unroll
            for (int rb = 0; rb < 2; ++rb)
#pragma unroll
                for (int c = 0; c < 4; ++c)
#pragma unroll
                    for (int e = 0; e < 4; ++e) acc[rb][c][e] = b2v[c];

            __builtin_amdgcn_s_setprio(1);
#pragma unroll
            for (int q = 0; q < 8; ++q) {
                short8 a0 = slot[q * 64];          // Rb = 0
                short8 a1 = slot[(8 + q) * 64];    // Rb = 1
#pragma unroll
                for (int c = 0; c < 4; ++c) {
                    acc[0][c] = __builtin_amdgcn_mfma_f32_16x16x32_bf16(a0, bfr[c][q], acc[0][c], 0, 0, 0);
                    acc[1][c] = __builtin_amdgcn_mfma_f32_16x16x32_bf16(a1, bfr[c][q], acc[1][c], 0, 0, 0);
                }
            }
            __builtin_amdgcn_s_setprio(0);
            if (lane == 0) atomicAdd(&done_f[s], 1u);   // LDS ops in-order: reads done

            float sa = 0.f, sb = 0.f, sc = 0.f, sd = 0.f;
#pragma unroll
            for (int e = 0; e < 4; ++e) {
                sa += fmaxf(acc[0][0][e], 0.f) + fmaxf(acc[1][0][e], 0.f);
                sb += fmaxf(acc[0][1][e], 0.f) + fmaxf(acc[1][1][e], 0.f);
                sc += fmaxf(acc[0][2][e], 0.f) + fmaxf(acc[1][2][e], 0.f);
                sd += fmaxf(acc[0][3][e], 0.f) + fmaxf(acc[1][3][e], 0.f);
            }
            js[0] += sa; js[1] += sb; js[2] += sc; js[3] += sd;
        }
#pragma unroll
        for (int c = 0; c < 4; ++c) {
            js[c] += __shfl_xor(js[c], 16);
            js[c] += __shfl_xor(js[c], 32);
        }
        if (lane < 16) {
#pragma unroll
            for (int c = 0; c < 4; ++c)
                partials[((size_t)(b * 256 + cts[c] * 16 + lane)) * 128 + cq] = js[c];
        }
    } else {
        // ========== PRODUCER pw: tiles t = pw, pw+4, ...; 16x16 frag layout ==========
        const int pw = w - 4;
        const int ip = l31 & 7, cq4 = l31 >> 3;   // tile row l31 = cq4*8 + ip
        const float* __restrict__ hrowb = hi_ + (size_t)b * 131072
                                        + (size_t)ip * 256 + h * 8;
        const float* __restrict__ crow  = hcb_ + (size_t)b * 131072
                                        + (size_t)(cq * 4 + cq4) * 256 + h * 8;
        // dst base: Rb*512 + (l31&15) + 16*h ; per kk add (kk>>1)*64 + (kk&1)*32
        const int wbase = (l31 >> 4) * 512 + (l31 & 15) + 16 * h;
#pragma unroll 1
        for (int t = pw; t < 64; t += 4) {
            const int s = t % 6;
            while (vdone[s] != 4u) __builtin_amdgcn_s_sleep(1);
            if (lane == 0) vdone[s] = 0u;
            const float* __restrict__ hrow = hrowb + (size_t)t * (8 * 256);
            short8* __restrict__ slot = &ring[s][0];
#pragma unroll
            for (int kk = 0; kk < 16; ++kk) {
                float4v x0 = *reinterpret_cast<const float4v*>(hrow + kk * 16);
                float4v x1 = *reinterpret_cast<const float4v*>(hrow + kk * 16 + 4);
                float4v c0 = *reinterpret_cast<const float4v*>(crow + kk * 16);
                float4v c1 = *reinterpret_cast<const float4v*>(crow + kk * 16 + 4);
                slot[wbase + (kk >> 1) * 64 + (kk & 1) * 32] = relu_pack8(x0 + c0, x1 + c1);
            }
            asm volatile("s_waitcnt lgkmcnt(0)" ::: "memory");
            if (lane == 0) vready[s] = (unsigned)(t + 1);
        }
    }
}

// ---- reduceK: 512 blocks (one per (b,col)) x 128 thr; sums 128 slots
__global__ __launch_bounds__(128) void reduceK(const float* __restrict__ partials,
                                               float* __restrict__ su_g) {
    int tid = threadIdx.x, blk = blockIdx.x;      // blk = b*256 + col
    float s = partials[(size_t)blk * 128 + tid];
#pragma unroll
    for (int d = 1; d < 64; d <<= 1) s += __shfl_xor(s, d);
    __shared__ float ws[2];
    if ((tid & 63) == 0) ws[tid >> 6] = s;
    __syncthreads();
    if (tid == 0) su_g[blk] = ws[0] + ws[1];
}

// ---- final tail MLP (reads 512-float su_g), 512 thr
__global__ __launch_bounds__(512) void finalK(const float* __restrict__ su_g,
                                              const float* __restrict__ w3,
                                              const float* __restrict__ b3,
                                              const float* __restrict__ w4,
                                              const float* __restrict__ b4,
                                              const float* __restrict__ w5,
                                              const float* __restrict__ b5,
                                              float* __restrict__ out) {
    __shared__ float su[2][256], mid[2][256], o[2][256];
    int tid = threadIdx.x;
    int b = tid >> 8, c = tid & 255;
    su[b][c] = su_g[b * 256 + c];
    __syncthreads();
    float m = 262144.0f * b3[c];
    for (int k = 0; k < 256; ++k) m += su[b][k] * w3[k * 256 + c];
    mid[b][c] = m;
    __syncthreads();
    float ov = b4[c];
    for (int k = 0; k < 256; ++k) ov += mid[b][k] * w4[k * 256 + c];
    o[b][c] = fmaxf(ov, 0.f);
    __syncthreads();
    if (c < 64) {
        float rr = b5[c];
        for (int k = 0; k < 256; ++k) rr += o[b][k] * w5[k * 64 + c];
        out[b * 64 + c] = rr;
    }
}

extern "C" void kernel_launch(void* const* d_in, const int* in_sizes, int n_in,
                              void* d_out, int out_size, void* d_ws, size_t ws_size,
                              hipStream_t stream) {
    const float* in = (const float*)d_in[0];
    const float* w1 = (const float*)d_in[1];
    const float* b1 = (const float*)d_in[2];
    const float* w2 = (const float*)d_in[3];
    const float* b2 = (const float*)d_in[4];
    const float* w3 = (const float*)d_in[5];
    const float* b3 = (const float*)d_in[6];
    const float* w4 = (const float*)d_in[7];
    const float* b4 = (const float*)d_in[8];
    const float* w5 = (const float*)d_in[9];
    const float* b5 = (const float*)d_in[10];
    float* out = (float*)d_out;

    char* ws = (char*)d_ws;
    float* hi       = (float*)(ws);                                   // 1 MB
    float* hcb      = (float*)(ws + (1u << 20));                      // 1 MB
    short* bfrag    = (short*)(ws + (2u << 20));                      // 128 KB
    float* partials = (float*)(ws + (2u << 20) + (1u << 18));         // 256 KB (2x256x128)
    float* su_g     = (float*)(ws + (2u << 20) + (2u << 18));         // 2 KB

    prep<<<512, 256, 0, stream>>>(in, w1, b1, w2, hi, hcb, bfrag);
    big<<<256, 512, 0, stream>>>(hi, hcb, (const short8*)bfrag, b2, partials);
    reduceK<<<512, 128, 0, stream>>>(partials, su_g);
    finalK<<<1, 512, 0, stream>>>(su_g, w3, b3, w4, b4, w5, b5, out);
}